// Round 8
// baseline (857.467 us; speedup 1.0000x reference)
//
#include <hip/hip_runtime.h>
#include <hip/hip_bf16.h>

typedef __attribute__((ext_vector_type(8))) short bf16x8;
typedef __attribute__((ext_vector_type(4))) float f32x4;

constexpr int ND = 128;   // node dim
constexpr int HD = 256;   // hidden dim
constexpr int ED = 64;    // edge dim
constexpr int ET = 64;    // edges per block tile
constexpr int MPn = 200;  // m pitch bf16
constexpr int HP  = 264;  // hid pitch bf16 (528B)
constexpr int MSGP = 132; // msg pitch f32 (528B)

// fast silu: v * rcp(1+exp(-v)) — avoids IEEE div expansion
__device__ __forceinline__ float silu_f(float v) {
    float e = __expf(-v);
    return v * __builtin_amdgcn_rcpf(1.0f + e);
}
__device__ __forceinline__ __hip_bfloat16 f2b(float v) { return __float2bfloat16(v); }
__device__ __forceinline__ unsigned short f2bu(float v) {
    __hip_bfloat16 b = __float2bfloat16(v);
    return *(unsigned short*)&b;
}
__device__ __forceinline__ float bu2f(unsigned short u) {
    unsigned int t = ((unsigned int)u) << 16;
    return __uint_as_float(t);
}

// ---------- fused prep: h -> bf16, and dst histogram ----------
__global__ __launch_bounds__(256) void prep_h_hist(
    const float* __restrict__ h, __hip_bfloat16* __restrict__ hb, int nh,
    const int* __restrict__ eidx, int* __restrict__ cnt, int E)
{
    int i = blockIdx.x * 256 + threadIdx.x;
    if (i < nh) hb[i] = f2b(h[i]);
    if (i < E)  atomicAdd(&cnt[eidx[E + i]], 1);
}

// ---------- fused prep: weights -> bf16 swizzled + bias folding ----------
// Wn1s/Wc1s: B-frag order, rows 256:320 folded with We2.
// Wn2s: B-frag order with k-source permuted to match swizzled hid cols:
//   k_orig(kk) = (kk>>6)*64 + (kk&3)*16 + ((kk>>2)&15)
__global__ __launch_bounds__(256) void prep_w(
    const float* __restrict__ Wn1, const float* __restrict__ Wc1,
    const float* __restrict__ Wn2, const float* __restrict__ We2,
    const float* __restrict__ bn1, const float* __restrict__ bc1,
    const float* __restrict__ be2,
    __hip_bfloat16* __restrict__ Wn1s, __hip_bfloat16* __restrict__ Wc1s,
    __hip_bfloat16* __restrict__ Wn2s,
    float* __restrict__ bn1p, float* __restrict__ bc1p)
{
    int id = blockIdx.x * 256 + threadIdx.x;
    if (id < 163840) {                      // Wn1s / Wc1s: 10 ks * 16 nt * 64 * 8
        int e = id;
        const float* W = Wn1; __hip_bfloat16* out = Wn1s;
        if (id >= 81920) { e -= 81920; W = Wc1; out = Wc1s; }
        int j = e & 7, lane = (e >> 3) & 63, nt = (e >> 9) & 15, ks = e >> 13;
        int k = ks * 32 + (lane >> 4) * 8 + j;
        int n = nt * 16 + (lane & 15);
        float v;
        if (k < 2 * ND) v = W[k * HD + n];
        else {
            int t = k - 2 * ND; v = 0.f;
            for (int u = 0; u < ED; ++u) v += We2[t * ED + u] * W[(2 * ND + u) * HD + n];
        }
        out[e] = f2b(v);
    } else if (id < 196608) {               // Wn2s: 8 ks * 8 nt * 64 * 8 (k permuted)
        int e = id - 163840;
        int j = e & 7, lane = (e >> 3) & 63, nt = (e >> 9) & 7, ks = e >> 12;
        int kk = ks * 32 + (lane >> 4) * 8 + j;
        int k = (kk >> 6) * 64 + (kk & 3) * 16 + ((kk >> 2) & 15);
        int n = nt * 16 + (lane & 15);
        Wn2s[e] = f2b(Wn2[k * ND + n]);
    } else if (id < 197120) {               // folded biases
        int n = id - 196608;
        if (n < HD) {
            float v = bn1[n];
            for (int t = 0; t < ED; ++t) v += be2[t] * Wn1[(2 * ND + t) * HD + n];
            bn1p[n] = v;
        } else {
            int m = n - HD;
            float v = bc1[m];
            for (int t = 0; t < ED; ++t) v += be2[t] * Wc1[(2 * ND + t) * HD + m];
            bc1p[m] = v;
        }
    }
}

// ---------- prep: Q = h @ [Wn1_mid | Wc1_mid], pass-separated C-frag packed ----------
// ushort4 (nti0..3) at ((node*2 + pass)*64 + wv*16 + lc)  [512B contiguous per (node,pass)]
__global__ __launch_bounds__(256) void prep_q(
    const __hip_bfloat16* __restrict__ hb,
    const __hip_bfloat16* __restrict__ Wn1s,
    const __hip_bfloat16* __restrict__ Wc1s,
    unsigned short* __restrict__ Q, int N)
{
    __shared__ __align__(16) __hip_bfloat16 a_sh[64 * 136];  // pitch 272B
    const int tid = threadIdx.x;
    const int lane = tid & 63, wv = tid >> 6;
    const int q = lane >> 4, lc = lane & 15;
    const int row0 = blockIdx.x * 64;

    for (int i = tid; i < 64 * 16; i += 256) {
        int r = i >> 4, piece = i & 15;
        int node = min(row0 + r, N - 1);
        uint4 v = ((const uint4*)(hb + (size_t)node * ND))[piece];
        *((uint4*)((char*)a_sh + r * 272 + piece * 16)) = v;
    }
    __syncthreads();

    for (int pass = 0; pass < 2; ++pass) {
        const __hip_bfloat16* Ws = pass ? Wc1s : Wn1s;
        f32x4 acc[4][4];
        #pragma unroll
        for (int rt = 0; rt < 4; ++rt)
            #pragma unroll
            for (int nti = 0; nti < 4; ++nti) acc[rt][nti] = (f32x4){0.f, 0.f, 0.f, 0.f};

        for (int ks = 0; ks < 4; ++ks) {
            bf16x8 a[4];
            #pragma unroll
            for (int rt = 0; rt < 4; ++rt)
                a[rt] = *(const bf16x8*)&a_sh[(rt * 16 + lc) * 136 + ks * 32 + q * 8];
            #pragma unroll
            for (int nti = 0; nti < 4; ++nti) {
                bf16x8 b = *(const bf16x8*)&Ws[(((ks + 4) * 16 + wv * 4 + nti) * 64 + lane) * 8];
                #pragma unroll
                for (int rt = 0; rt < 4; ++rt)
                    acc[rt][nti] = __builtin_amdgcn_mfma_f32_16x16x32_bf16(a[rt], b, acc[rt][nti], 0, 0, 0);
            }
        }
        #pragma unroll
        for (int rt = 0; rt < 4; ++rt)
            #pragma unroll
            for (int r = 0; r < 4; ++r) {
                int node = row0 + rt * 16 + q * 4 + r;
                if (node < N) {
                    ushort4 us;
                    us.x = f2bu(acc[rt][0][r]); us.y = f2bu(acc[rt][1][r]);
                    us.z = f2bu(acc[rt][2][r]); us.w = f2bu(acc[rt][3][r]);
                    ((ushort4*)Q)[((size_t)node * 2 + pass) * 64 + wv * 16 + lc] = us;
                }
            }
    }
}

// ---------- counting sort by dst ----------
__global__ __launch_bounds__(256) void s_scan1(const int* __restrict__ cnt,
                                               int* __restrict__ bsum, int N) {
    __shared__ int sh[256];
    int i = blockIdx.x * 256 + threadIdx.x;
    sh[threadIdx.x] = (i < N) ? cnt[i] : 0;
    __syncthreads();
    for (int s = 128; s > 0; s >>= 1) {
        if (threadIdx.x < s) sh[threadIdx.x] += sh[threadIdx.x + s];
        __syncthreads();
    }
    if (threadIdx.x == 0) bsum[blockIdx.x] = sh[0];
}

__global__ __launch_bounds__(256) void s_scan2(int* __restrict__ bsum, int nb) {
    __shared__ int sh[256];
    int t = threadIdx.x;
    int orig = (t < nb) ? bsum[t] : 0;
    sh[t] = orig;
    __syncthreads();
    for (int off = 1; off < 256; off <<= 1) {
        int u = (t >= off) ? sh[t - off] : 0;
        __syncthreads();
        sh[t] += u;
        __syncthreads();
    }
    if (t < nb) bsum[t] = sh[t] - orig;   // exclusive
}

__global__ __launch_bounds__(256) void s_scan3(const int* __restrict__ cnt,
                                               const int* __restrict__ bsum,
                                               int* __restrict__ head, int N) {
    __shared__ int sh[256];
    int t = threadIdx.x, i = blockIdx.x * 256 + t;
    int v = (i < N) ? cnt[i] : 0;
    sh[t] = v;
    __syncthreads();
    for (int off = 1; off < 256; off <<= 1) {
        int u = (t >= off) ? sh[t - off] : 0;
        __syncthreads();
        sh[t] += u;
        __syncthreads();
    }
    if (i < N) head[i] = bsum[blockIdx.x] + sh[t] - v;  // exclusive prefix
}

__global__ __launch_bounds__(256) void s_scatter(
    const int* __restrict__ eidx, const float* __restrict__ dist,
    int* __restrict__ head, int4* __restrict__ sedge, int E)
{
    int e = blockIdx.x * 256 + threadIdx.x;
    if (e < E) {
        int d = eidx[E + e];
        int pos = atomicAdd(&head[d], 1);
        int4 v; v.x = eidx[e]; v.y = d; v.z = __float_as_int(dist[e]); v.w = 0;
        sedge[pos] = v;
    }
}

// ---------- main fused edge kernel ----------
__global__ __launch_bounds__(256, 4) void egnn_main(
    const __hip_bfloat16* __restrict__ hb,
    const float* __restrict__ x,
    const int4* __restrict__ sedge,
    const __hip_bfloat16* __restrict__ Wn1s,
    const __hip_bfloat16* __restrict__ Wc1s,
    const __hip_bfloat16* __restrict__ Wn2s,
    const unsigned short* __restrict__ Q,
    const float* __restrict__ bn1p, const float* __restrict__ bc1p,
    const float* __restrict__ bn2,  const float* __restrict__ Wc2,
    const float* __restrict__ We1,  const float* __restrict__ be1,
    float* __restrict__ h_agg, float* __restrict__ x_agg,
    int E)
{
    __shared__ __align__(16) unsigned char smem[ET * HP * 2];
    __shared__ float dir_sh[ET * 3];
    __shared__ float coordw_sh[ET];
    __shared__ float dist_sh[ET];
    __shared__ int   sidx[ET], didx[ET];

    __hip_bfloat16* m_sh = (__hip_bfloat16*)smem;

    const int tid  = threadIdx.x;
    const int lane = tid & 63;
    const int wv   = tid >> 6;
    const int q    = lane >> 4;
    const int lc   = lane & 15;

    // XCD-aware swizzle: consecutive logical blocks (= consecutive dst ranges)
    // land on the same XCD -> Q/h_agg slices stay hot in that XCD's L2.
    const int G = gridDim.x;
    const int per = G >> 3, rem = G & 7;
    const int xcd = blockIdx.x & 7, slot = blockIdx.x >> 3;
    const int logical = (xcd < rem) ? xcd * (per + 1) + slot
                                    : rem * (per + 1) + (xcd - rem) * per + slot;
    const int e0 = logical * ET;

    if (tid < ET) {
        int e = min(e0 + tid, E - 1);
        int4 v = sedge[e];
        int s = v.x, d = v.y;
        sidx[tid] = s; didx[tid] = d;
        dist_sh[tid] = __int_as_float(v.z);
        coordw_sh[tid] = 0.f;
        #pragma unroll
        for (int c = 0; c < 3; ++c) dir_sh[tid * 3 + c] = x[s * 3 + c] - x[d * 3 + c];
    }
    __syncthreads();

    // gather h[src] -> m[:,0:128]
    for (int i = tid; i < ET * 16; i += 256) {
        int er = i >> 4, piece = i & 15;
        uint4 v = ((const uint4*)(hb + (size_t)sidx[er] * ND))[piece];
        *((uint4*)((char*)m_sh + er * (MPn * 2) + piece * 16)) = v;
    }
    // se = silu(dist*We1+be1) -> m[:,128:192]
    for (int i = tid; i < ET * ED; i += 256) {
        int er = i >> 6, j = i & 63;
        m_sh[er * MPn + ND + j] = f2b(silu_f(fmaf(dist_sh[er], We1[j], be1[j])));
    }
    __syncthreads();

    // cache dst ids for this lane's 16 accumulator rows
    int ddv[4][4];
    #pragma unroll
    for (int rt = 0; rt < 4; ++rt)
        #pragma unroll
        for (int r = 0; r < 4; ++r) ddv[rt][r] = didx[rt * 16 + q * 4 + r];

    // ---- GEMM1 pass A: coord hidden = [h_src|se]@Wc' + Q[dst][coord] + bias ----
    {
        f32x4 acc[4][4];
        #pragma unroll
        for (int nti = 0; nti < 4; ++nti) {
            float b = bc1p[(wv * 4 + nti) * 16 + lc];
            #pragma unroll
            for (int rt = 0; rt < 4; ++rt) acc[rt][nti] = (f32x4){b, b, b, b};
        }
        for (int ks = 0; ks < 6; ++ks) {
            int bk = (ks < 4) ? ks : ks + 4;
            bf16x8 a[4];
            #pragma unroll
            for (int rt = 0; rt < 4; ++rt)
                a[rt] = *(const bf16x8*)&m_sh[(rt * 16 + lc) * MPn + ks * 32 + q * 8];
            #pragma unroll
            for (int nti = 0; nti < 4; ++nti) {
                bf16x8 b = *(const bf16x8*)&Wc1s[((bk * 16 + wv * 4 + nti) * 64 + lane) * 8];
                #pragma unroll
                for (int rt = 0; rt < 4; ++rt)
                    acc[rt][nti] = __builtin_amdgcn_mfma_f32_16x16x32_bf16(a[rt], b, acc[rt][nti], 0, 0, 0);
            }
        }
        float wcv[4];
        #pragma unroll
        for (int nti = 0; nti < 4; ++nti) wcv[nti] = Wc2[(wv * 4 + nti) * 16 + lc];
        #pragma unroll
        for (int rt = 0; rt < 4; ++rt) {
            float p[4];
            #pragma unroll
            for (int r = 0; r < 4; ++r) {
                ushort4 us = ((const ushort4*)Q)[((size_t)ddv[rt][r] * 2 + 1) * 64 + wv * 16 + lc];
                float pv = 0.f;
                pv += silu_f(acc[rt][0][r] + bu2f(us.x)) * wcv[0];
                pv += silu_f(acc[rt][1][r] + bu2f(us.y)) * wcv[1];
                pv += silu_f(acc[rt][2][r] + bu2f(us.z)) * wcv[2];
                pv += silu_f(acc[rt][3][r] + bu2f(us.w)) * wcv[3];
                p[r] = pv;
            }
            #pragma unroll
            for (int r = 0; r < 4; ++r) {
                float v = p[r];
                v += __shfl_xor(v, 1); v += __shfl_xor(v, 2);
                v += __shfl_xor(v, 4); v += __shfl_xor(v, 8);
                if (lc == 0) atomicAdd(&coordw_sh[rt * 16 + q * 4 + r], v);
            }
        }
    }

    // ---- GEMM1 pass B: node hidden ----
    f32x4 accn[4][4];
    #pragma unroll
    for (int nti = 0; nti < 4; ++nti) {
        float b = bn1p[(wv * 4 + nti) * 16 + lc];
        #pragma unroll
        for (int rt = 0; rt < 4; ++rt) accn[rt][nti] = (f32x4){b, b, b, b};
    }
    for (int ks = 0; ks < 6; ++ks) {
        int bk = (ks < 4) ? ks : ks + 4;
        bf16x8 a[4];
        #pragma unroll
        for (int rt = 0; rt < 4; ++rt)
            a[rt] = *(const bf16x8*)&m_sh[(rt * 16 + lc) * MPn + ks * 32 + q * 8];
        #pragma unroll
        for (int nti = 0; nti < 4; ++nti) {
            bf16x8 b = *(const bf16x8*)&Wn1s[((bk * 16 + wv * 4 + nti) * 64 + lane) * 8];
            #pragma unroll
            for (int rt = 0; rt < 4; ++rt)
                accn[rt][nti] = __builtin_amdgcn_mfma_f32_16x16x32_bf16(a[rt], b, accn[rt][nti], 0, 0, 0);
        }
    }
    __syncthreads();   // all waves done reading m_sh

    // hid = silu(accn + Q[dst][node]), col-swizzled (c' = wv*64 + lc*4 + nti), b64 writes
    __hip_bfloat16* hid = (__hip_bfloat16*)smem;
    #pragma unroll
    for (int rt = 0; rt < 4; ++rt) {
        #pragma unroll
        for (int r = 0; r < 4; ++r) {
            int row = rt * 16 + q * 4 + r;
            ushort4 us = ((const ushort4*)Q)[(size_t)ddv[rt][r] * 2 * 64 + wv * 16 + lc];
            ushort4 hv;
            hv.x = f2bu(silu_f(accn[rt][0][r] + bu2f(us.x)));
            hv.y = f2bu(silu_f(accn[rt][1][r] + bu2f(us.y)));
            hv.z = f2bu(silu_f(accn[rt][2][r] + bu2f(us.z)));
            hv.w = f2bu(silu_f(accn[rt][3][r] + bu2f(us.w)));
            *(ushort4*)&hid[row * HP + wv * 64 + lc * 4] = hv;
        }
    }
    __syncthreads();

    // ---- GEMM2: msg = hid @ Wn2 + bn2 (Wn2s k-permuted to match swizzle) ----
    f32x4 acc2[4][2];
    #pragma unroll
    for (int nti = 0; nti < 2; ++nti) {
        float b = bn2[(wv * 2 + nti) * 16 + lc];
        #pragma unroll
        for (int rt = 0; rt < 4; ++rt) acc2[rt][nti] = (f32x4){b, b, b, b};
    }
    for (int ks = 0; ks < 8; ++ks) {
        bf16x8 a[4];
        #pragma unroll
        for (int rt = 0; rt < 4; ++rt)
            a[rt] = *(const bf16x8*)&hid[(rt * 16 + lc) * HP + ks * 32 + q * 8];
        #pragma unroll
        for (int nti = 0; nti < 2; ++nti) {
            bf16x8 b = *(const bf16x8*)&Wn2s[((ks * 8 + wv * 2 + nti) * 64 + lane) * 8];
            #pragma unroll
            for (int rt = 0; rt < 4; ++rt)
                acc2[rt][nti] = __builtin_amdgcn_mfma_f32_16x16x32_bf16(a[rt], b, acc2[rt][nti], 0, 0, 0);
        }
    }
    __syncthreads();   // waves done reading hid

    // msg col-swizzled (c'' = wv*32 + lc*2 + nti), float2 writes
    float* msg = (float*)smem;
    #pragma unroll
    for (int rt = 0; rt < 4; ++rt)
        #pragma unroll
        for (int r = 0; r < 4; ++r) {
            int row = rt * 16 + q * 4 + r;
            float2 mv; mv.x = acc2[rt][0][r]; mv.y = acc2[rt][1][r];
            *(float2*)&msg[row * MSGP + wv * 32 + lc * 2] = mv;
        }
    __syncthreads();

    // ---- segmented flush: 256 threads, 32 col-groups x 8 row-groups ----
    {
        int cg = (tid & 31) * 4;
        int r0 = (tid >> 5) * 8;
        f32x4 run = (f32x4){0.f, 0.f, 0.f, 0.f};
        int cur = -1;
        for (int r = r0; r < r0 + 8; ++r) {
            int d = (e0 + r < E) ? didx[r] : -1;
            if (d != cur) {
                if (cur >= 0) {
                    float* dst = &h_agg[(size_t)cur * ND + cg];
                    atomicAdd(dst + 0, run[0]); atomicAdd(dst + 1, run[1]);
                    atomicAdd(dst + 2, run[2]); atomicAdd(dst + 3, run[3]);
                }
                run = (f32x4){0.f, 0.f, 0.f, 0.f}; cur = d;
            }
            if (d >= 0) run += *(const f32x4*)&msg[r * MSGP + cg];
        }
        if (cur >= 0) {
            float* dst = &h_agg[(size_t)cur * ND + cg];
            atomicAdd(dst + 0, run[0]); atomicAdd(dst + 1, run[1]);
            atomicAdd(dst + 2, run[2]); atomicAdd(dst + 3, run[3]);
        }
    }
    if (tid < 6) {
        int c = tid % 3, r0 = (tid / 3) * 32;
        float run = 0.f; int cur = -1;
        for (int r = r0; r < r0 + 32; ++r) {
            int d = (e0 + r < E) ? didx[r] : -1;
            if (d != cur) {
                if (cur >= 0) atomicAdd(&x_agg[cur * 3 + c], run);
                run = 0.f; cur = d;
            }
            if (d >= 0) run += coordw_sh[r] * dir_sh[r * 3 + c];
        }
        if (cur >= 0) atomicAdd(&x_agg[cur * 3 + c], run);
    }
}

__global__ __launch_bounds__(256) void egnn_finalize(
    const float* __restrict__ h, const float* __restrict__ x,
    const float* __restrict__ h_agg, const float* __restrict__ x_agg,
    float* __restrict__ out, int n_nodes)
{
    int i = blockIdx.x * 256 + threadIdx.x;
    int nh = n_nodes * ND;
    int total = nh + n_nodes * 3;
    if (i < nh) {
        int c = i & 127;
        int csw = (c >> 5) * 32 + (c & 15) * 2 + ((c >> 4) & 1);  // unswizzle msg cols
        out[i] = h[i] + h_agg[(size_t)(i >> 7) * ND + csw];
    } else if (i < total) { int k = i - nh; out[i] = x[k] + x_agg[k]; }
}

extern "C" void kernel_launch(void* const* d_in, const int* in_sizes, int n_in,
                              void* d_out, int out_size, void* d_ws, size_t ws_size,
                              hipStream_t stream)
{
    const float* h    = (const float*)d_in[0];
    const float* x    = (const float*)d_in[1];
    const int*   eidx = (const int*)d_in[2];
    const float* dist = (const float*)d_in[3];
    const float* Wn1  = (const float*)d_in[4];
    const float* bn1  = (const float*)d_in[5];
    const float* Wn2  = (const float*)d_in[6];
    const float* bn2  = (const float*)d_in[7];
    const float* Wc1  = (const float*)d_in[8];
    const float* bc1  = (const float*)d_in[9];
    const float* Wc2  = (const float*)d_in[10];
    const float* We1  = (const float*)d_in[11];
    const float* be1  = (const float*)d_in[12];
    const float* We2  = (const float*)d_in[13];
    const float* be2  = (const float*)d_in[14];

    const int E = in_sizes[3];
    const int N = in_sizes[0] / ND;

    // workspace layout (16B-aligned segments)
    float* h_agg = (float*)d_ws;                           // N*ND (swizzled cols)
    float* x_agg = h_agg + (size_t)N * ND;                 // N*3
    float* bn1p  = x_agg + (size_t)N * 3;                  // HD
    float* bc1p  = bn1p + HD;                              // HD
    __hip_bfloat16* hb   = (__hip_bfloat16*)(bc1p + HD);   // N*ND bf16
    __hip_bfloat16* Wn1s = hb + (size_t)N * ND;            // 81920
    __hip_bfloat16* Wc1s = Wn1s + 81920;                   // 81920
    __hip_bfloat16* Wn2s = Wc1s + 81920;                   // 32768
    int*   cnt   = (int*)(Wn2s + 32768);                   // N
    int*   bsum  = cnt + N;                                // 256
    int*   head  = bsum + 256;                             // N
    int4*  sedge = (int4*)(head + N);                      // E int4
    unsigned short* Q = (unsigned short*)(sedge + E);      // N*512

    hipMemsetAsync(d_ws, 0, ((size_t)N * ND + (size_t)N * 3) * sizeof(float), stream);
    hipMemsetAsync(cnt, 0, (size_t)N * sizeof(int), stream);

    const int nbN = (N + 255) / 256;
    const int nbE = (E + 255) / 256;
    const int nh  = N * ND;
    const int nbH = (nh > E ? nh + 255 : E + 255) / 256;

    prep_h_hist<<<nbH, 256, 0, stream>>>(h, hb, nh, eidx, cnt, E);
    s_scan1  <<<nbN, 256, 0, stream>>>(cnt, bsum, N);
    s_scan2  <<<1,   256, 0, stream>>>(bsum, nbN);
    s_scan3  <<<nbN, 256, 0, stream>>>(cnt, bsum, head, N);
    s_scatter<<<nbE, 256, 0, stream>>>(eidx, dist, head, sedge, E);

    prep_w<<<770, 256, 0, stream>>>(Wn1, Wc1, Wn2, We2, bn1, bc1, be2,
                                    Wn1s, Wc1s, Wn2s, bn1p, bc1p);
    prep_q<<<(N + 63) / 64, 256, 0, stream>>>(hb, Wn1s, Wc1s, Q, N);

    egnn_main<<<(E + ET - 1) / ET, 256, 0, stream>>>(
        hb, x, sedge, Wn1s, Wc1s, Wn2s, Q, bn1p, bc1p, bn2, Wc2,
        We1, be1, h_agg, x_agg, E);

    int total = N * ND + N * 3;
    egnn_finalize<<<(total + 255) / 256, 256, 0, stream>>>(
        h, x, h_agg, x_agg, (float*)d_out, N);
}

// Round 9
// 778.704 us; speedup vs baseline: 1.1011x; 1.1011x over previous
//
#include <hip/hip_runtime.h>
#include <hip/hip_bf16.h>

typedef __attribute__((ext_vector_type(8))) short bf16x8;
typedef __attribute__((ext_vector_type(4))) float f32x4;

constexpr int ND = 128;   // node dim
constexpr int HD = 256;   // hidden dim
constexpr int ED = 64;    // edge dim
constexpr int ET = 64;    // edges per block tile
constexpr int MPn = 200;  // m pitch bf16
constexpr int HP  = 264;  // hid pitch bf16 (528B)
constexpr int MSGP = 132; // msg pitch f32 (528B)

// fast silu: v * rcp(1+exp(-v)) — avoids IEEE div expansion
__device__ __forceinline__ float silu_f(float v) {
    float e = __expf(-v);
    return v * __builtin_amdgcn_rcpf(1.0f + e);
}
__device__ __forceinline__ __hip_bfloat16 f2b(float v) { return __float2bfloat16(v); }
__device__ __forceinline__ unsigned short f2bu(float v) {
    __hip_bfloat16 b = __float2bfloat16(v);
    return *(unsigned short*)&b;
}
__device__ __forceinline__ float bu2f(unsigned short u) {
    unsigned int t = ((unsigned int)u) << 16;
    return __uint_as_float(t);
}

// ---------- fused prep: h -> bf16, and dst histogram ----------
__global__ __launch_bounds__(256) void prep_h_hist(
    const float* __restrict__ h, __hip_bfloat16* __restrict__ hb, int nh,
    const int* __restrict__ eidx, int* __restrict__ cnt, int E)
{
    int i = blockIdx.x * 256 + threadIdx.x;
    if (i < nh) hb[i] = f2b(h[i]);
    if (i < E)  atomicAdd(&cnt[eidx[E + i]], 1);
}

// ---------- fused prep: weights -> bf16 swizzled + bias folding ----------
__global__ __launch_bounds__(256) void prep_w(
    const float* __restrict__ Wn1, const float* __restrict__ Wc1,
    const float* __restrict__ Wn2, const float* __restrict__ We2,
    const float* __restrict__ bn1, const float* __restrict__ bc1,
    const float* __restrict__ be2,
    __hip_bfloat16* __restrict__ Wn1s, __hip_bfloat16* __restrict__ Wc1s,
    __hip_bfloat16* __restrict__ Wn2s,
    float* __restrict__ bn1p, float* __restrict__ bc1p)
{
    int id = blockIdx.x * 256 + threadIdx.x;
    if (id < 163840) {                      // Wn1s / Wc1s: 10 ks * 16 nt * 64 * 8
        int e = id;
        const float* W = Wn1; __hip_bfloat16* out = Wn1s;
        if (id >= 81920) { e -= 81920; W = Wc1; out = Wc1s; }
        int j = e & 7, lane = (e >> 3) & 63, nt = (e >> 9) & 15, ks = e >> 13;
        int k = ks * 32 + (lane >> 4) * 8 + j;
        int n = nt * 16 + (lane & 15);
        float v;
        if (k < 2 * ND) v = W[k * HD + n];
        else {
            int t = k - 2 * ND; v = 0.f;
            for (int u = 0; u < ED; ++u) v += We2[t * ED + u] * W[(2 * ND + u) * HD + n];
        }
        out[e] = f2b(v);
    } else if (id < 196608) {               // Wn2s: k permuted to swizzled hid cols
        int e = id - 163840;
        int j = e & 7, lane = (e >> 3) & 63, nt = (e >> 9) & 7, ks = e >> 12;
        int kk = ks * 32 + (lane >> 4) * 8 + j;
        int k = (kk >> 6) * 64 + (kk & 3) * 16 + ((kk >> 2) & 15);
        int n = nt * 16 + (lane & 15);
        Wn2s[e] = f2b(Wn2[k * ND + n]);
    } else if (id < 197120) {               // folded biases
        int n = id - 196608;
        if (n < HD) {
            float v = bn1[n];
            for (int t = 0; t < ED; ++t) v += be2[t] * Wn1[(2 * ND + t) * HD + n];
            bn1p[n] = v;
        } else {
            int m = n - HD;
            float v = bc1[m];
            for (int t = 0; t < ED; ++t) v += be2[t] * Wc1[(2 * ND + t) * HD + m];
            bc1p[m] = v;
        }
    }
}

// ---------- prep: Q = h @ [Wn1_mid | Wc1_mid], pass-separated C-frag packed ----------
__global__ __launch_bounds__(256) void prep_q(
    const __hip_bfloat16* __restrict__ hb,
    const __hip_bfloat16* __restrict__ Wn1s,
    const __hip_bfloat16* __restrict__ Wc1s,
    unsigned short* __restrict__ Q, int N)
{
    __shared__ __align__(16) __hip_bfloat16 a_sh[64 * 136];
    const int tid = threadIdx.x;
    const int lane = tid & 63, wv = tid >> 6;
    const int q = lane >> 4, lc = lane & 15;
    const int row0 = blockIdx.x * 64;

    for (int i = tid; i < 64 * 16; i += 256) {
        int r = i >> 4, piece = i & 15;
        int node = min(row0 + r, N - 1);
        uint4 v = ((const uint4*)(hb + (size_t)node * ND))[piece];
        *((uint4*)((char*)a_sh + r * 272 + piece * 16)) = v;
    }
    __syncthreads();

    for (int pass = 0; pass < 2; ++pass) {
        const __hip_bfloat16* Ws = pass ? Wc1s : Wn1s;
        f32x4 acc[4][4];
        #pragma unroll
        for (int rt = 0; rt < 4; ++rt)
            #pragma unroll
            for (int nti = 0; nti < 4; ++nti) acc[rt][nti] = (f32x4){0.f, 0.f, 0.f, 0.f};

        for (int ks = 0; ks < 4; ++ks) {
            bf16x8 a[4];
            #pragma unroll
            for (int rt = 0; rt < 4; ++rt)
                a[rt] = *(const bf16x8*)&a_sh[(rt * 16 + lc) * 136 + ks * 32 + q * 8];
            #pragma unroll
            for (int nti = 0; nti < 4; ++nti) {
                bf16x8 b = *(const bf16x8*)&Ws[(((ks + 4) * 16 + wv * 4 + nti) * 64 + lane) * 8];
                #pragma unroll
                for (int rt = 0; rt < 4; ++rt)
                    acc[rt][nti] = __builtin_amdgcn_mfma_f32_16x16x32_bf16(a[rt], b, acc[rt][nti], 0, 0, 0);
            }
        }
        #pragma unroll
        for (int rt = 0; rt < 4; ++rt)
            #pragma unroll
            for (int r = 0; r < 4; ++r) {
                int node = row0 + rt * 16 + q * 4 + r;
                if (node < N) {
                    ushort4 us;
                    us.x = f2bu(acc[rt][0][r]); us.y = f2bu(acc[rt][1][r]);
                    us.z = f2bu(acc[rt][2][r]); us.w = f2bu(acc[rt][3][r]);
                    ((ushort4*)Q)[((size_t)node * 2 + pass) * 64 + wv * 16 + lc] = us;
                }
            }
    }
}

// ---------- counting sort by dst ----------
__global__ __launch_bounds__(256) void s_scan1(const int* __restrict__ cnt,
                                               int* __restrict__ bsum, int N) {
    __shared__ int sh[256];
    int i = blockIdx.x * 256 + threadIdx.x;
    sh[threadIdx.x] = (i < N) ? cnt[i] : 0;
    __syncthreads();
    for (int s = 128; s > 0; s >>= 1) {
        if (threadIdx.x < s) sh[threadIdx.x] += sh[threadIdx.x + s];
        __syncthreads();
    }
    if (threadIdx.x == 0) bsum[blockIdx.x] = sh[0];
}

__global__ __launch_bounds__(256) void s_scan2(int* __restrict__ bsum, int nb) {
    __shared__ int sh[256];
    int t = threadIdx.x;
    int orig = (t < nb) ? bsum[t] : 0;
    sh[t] = orig;
    __syncthreads();
    for (int off = 1; off < 256; off <<= 1) {
        int u = (t >= off) ? sh[t - off] : 0;
        __syncthreads();
        sh[t] += u;
        __syncthreads();
    }
    if (t < nb) bsum[t] = sh[t] - orig;   // exclusive
}

__global__ __launch_bounds__(256) void s_scan3(const int* __restrict__ cnt,
                                               const int* __restrict__ bsum,
                                               int* __restrict__ head, int N) {
    __shared__ int sh[256];
    int t = threadIdx.x, i = blockIdx.x * 256 + t;
    int v = (i < N) ? cnt[i] : 0;
    sh[t] = v;
    __syncthreads();
    for (int off = 1; off < 256; off <<= 1) {
        int u = (t >= off) ? sh[t - off] : 0;
        __syncthreads();
        sh[t] += u;
        __syncthreads();
    }
    if (i < N) head[i] = bsum[blockIdx.x] + sh[t] - v;  // exclusive prefix
}

__global__ __launch_bounds__(256) void s_scatter(
    const int* __restrict__ eidx, const float* __restrict__ dist,
    int* __restrict__ head, int4* __restrict__ sedge, int E)
{
    int e = blockIdx.x * 256 + threadIdx.x;
    if (e < E) {
        int d = eidx[E + e];
        int pos = atomicAdd(&head[d], 1);
        int4 v; v.x = eidx[e]; v.y = d; v.z = __float_as_int(dist[e]); v.w = 0;
        sedge[pos] = v;
    }
}

// ---------- main fused edge kernel ----------
__global__ __launch_bounds__(256, 4) void egnn_main(
    const __hip_bfloat16* __restrict__ hb,
    const float* __restrict__ x,
    const int4* __restrict__ sedge,
    const __hip_bfloat16* __restrict__ Wn1s,
    const __hip_bfloat16* __restrict__ Wc1s,
    const __hip_bfloat16* __restrict__ Wn2s,
    const unsigned short* __restrict__ Q,
    const float* __restrict__ bn1p, const float* __restrict__ bc1p,
    const float* __restrict__ bn2,  const float* __restrict__ Wc2,
    const float* __restrict__ We1,  const float* __restrict__ be1,
    float* __restrict__ h_agg, float* __restrict__ x_agg,
    int E)
{
    __shared__ __align__(16) unsigned char smem[ET * HP * 2];
    __shared__ float dir_sh[ET * 3];
    __shared__ float coordw_sh[ET];
    __shared__ float dist_sh[ET];
    __shared__ int   sidx[ET], didx[ET];
    __shared__ int   seg_start[ET + 1];
    __shared__ int   nseg_sh;

    __hip_bfloat16* m_sh = (__hip_bfloat16*)smem;

    const int tid  = threadIdx.x;
    const int lane = tid & 63;
    const int wv   = tid >> 6;
    const int q    = lane >> 4;
    const int lc   = lane & 15;
    const int e0   = blockIdx.x * ET;       // plain mapping (XCD swizzle was a measured loss)
    const int nv   = min(ET, E - e0);

    if (tid < ET) {
        int e = min(e0 + tid, E - 1);
        int4 v = sedge[e];
        int s = v.x, d = v.y;
        sidx[tid] = s; didx[tid] = d;
        dist_sh[tid] = __int_as_float(v.z);
        coordw_sh[tid] = 0.f;
        #pragma unroll
        for (int c = 0; c < 3; ++c) dir_sh[tid * 3 + c] = x[s * 3 + c] - x[d * 3 + c];
    }
    __syncthreads();

    // segment table over valid rows (wave 0): seg_start[s], nseg
    if (wv == 0) {
        bool valid = lane < nv;
        bool flag = valid && (lane == 0 || didx[lane] != didx[lane - 1]);
        unsigned long long mask = __ballot(flag);
        if (flag) {
            int s = __popcll(mask & ((1ull << lane) - 1ull));
            seg_start[s] = lane;
        }
        if (lane == 0) {
            int ns = __popcll(mask);
            nseg_sh = ns;
            seg_start[ns] = nv;
        }
    }

    // gather h[src] -> m[:,0:128]
    for (int i = tid; i < ET * 16; i += 256) {
        int er = i >> 4, piece = i & 15;
        uint4 v = ((const uint4*)(hb + (size_t)sidx[er] * ND))[piece];
        *((uint4*)((char*)m_sh + er * (MPn * 2) + piece * 16)) = v;
    }
    // se = silu(dist*We1+be1) -> m[:,128:192]
    for (int i = tid; i < ET * ED; i += 256) {
        int er = i >> 6, j = i & 63;
        m_sh[er * MPn + ND + j] = f2b(silu_f(fmaf(dist_sh[er], We1[j], be1[j])));
    }
    __syncthreads();

    int ddv[4][4];
    #pragma unroll
    for (int rt = 0; rt < 4; ++rt)
        #pragma unroll
        for (int r = 0; r < 4; ++r) ddv[rt][r] = didx[rt * 16 + q * 4 + r];

    // ---- GEMM1 pass A: coord hidden = [h_src|se]@Wc' + Q[dst][coord] + bias ----
    {
        f32x4 acc[4][4];
        #pragma unroll
        for (int nti = 0; nti < 4; ++nti) {
            float b = bc1p[(wv * 4 + nti) * 16 + lc];
            #pragma unroll
            for (int rt = 0; rt < 4; ++rt) acc[rt][nti] = (f32x4){b, b, b, b};
        }
        for (int ks = 0; ks < 6; ++ks) {
            int bk = (ks < 4) ? ks : ks + 4;
            bf16x8 a[4];
            #pragma unroll
            for (int rt = 0; rt < 4; ++rt)
                a[rt] = *(const bf16x8*)&m_sh[(rt * 16 + lc) * MPn + ks * 32 + q * 8];
            #pragma unroll
            for (int nti = 0; nti < 4; ++nti) {
                bf16x8 b = *(const bf16x8*)&Wc1s[((bk * 16 + wv * 4 + nti) * 64 + lane) * 8];
                #pragma unroll
                for (int rt = 0; rt < 4; ++rt)
                    acc[rt][nti] = __builtin_amdgcn_mfma_f32_16x16x32_bf16(a[rt], b, acc[rt][nti], 0, 0, 0);
            }
        }
        float wcv[4];
        #pragma unroll
        for (int nti = 0; nti < 4; ++nti) wcv[nti] = Wc2[(wv * 4 + nti) * 16 + lc];
        #pragma unroll
        for (int rt = 0; rt < 4; ++rt) {
            float p[4];
            #pragma unroll
            for (int r = 0; r < 4; ++r) {
                ushort4 us = ((const ushort4*)Q)[((size_t)ddv[rt][r] * 2 + 1) * 64 + wv * 16 + lc];
                float pv = 0.f;
                pv += silu_f(acc[rt][0][r] + bu2f(us.x)) * wcv[0];
                pv += silu_f(acc[rt][1][r] + bu2f(us.y)) * wcv[1];
                pv += silu_f(acc[rt][2][r] + bu2f(us.z)) * wcv[2];
                pv += silu_f(acc[rt][3][r] + bu2f(us.w)) * wcv[3];
                p[r] = pv;
            }
            #pragma unroll
            for (int r = 0; r < 4; ++r) {
                float v = p[r];
                v += __shfl_xor(v, 1); v += __shfl_xor(v, 2);
                v += __shfl_xor(v, 4); v += __shfl_xor(v, 8);
                if (lc == 0) atomicAdd(&coordw_sh[rt * 16 + q * 4 + r], v);
            }
        }
    }

    // ---- GEMM1 pass B: node hidden ----
    f32x4 accn[4][4];
    #pragma unroll
    for (int nti = 0; nti < 4; ++nti) {
        float b = bn1p[(wv * 4 + nti) * 16 + lc];
        #pragma unroll
        for (int rt = 0; rt < 4; ++rt) accn[rt][nti] = (f32x4){b, b, b, b};
    }
    for (int ks = 0; ks < 6; ++ks) {
        int bk = (ks < 4) ? ks : ks + 4;
        bf16x8 a[4];
        #pragma unroll
        for (int rt = 0; rt < 4; ++rt)
            a[rt] = *(const bf16x8*)&m_sh[(rt * 16 + lc) * MPn + ks * 32 + q * 8];
        #pragma unroll
        for (int nti = 0; nti < 4; ++nti) {
            bf16x8 b = *(const bf16x8*)&Wn1s[((bk * 16 + wv * 4 + nti) * 64 + lane) * 8];
            #pragma unroll
            for (int rt = 0; rt < 4; ++rt)
                accn[rt][nti] = __builtin_amdgcn_mfma_f32_16x16x32_bf16(a[rt], b, accn[rt][nti], 0, 0, 0);
        }
    }
    __syncthreads();   // all waves done reading m_sh

    // hid = silu(accn + Q[dst][node]), col-swizzled (c' = wv*64 + lc*4 + nti)
    __hip_bfloat16* hid = (__hip_bfloat16*)smem;
    #pragma unroll
    for (int rt = 0; rt < 4; ++rt) {
        #pragma unroll
        for (int r = 0; r < 4; ++r) {
            int row = rt * 16 + q * 4 + r;
            ushort4 us = ((const ushort4*)Q)[(size_t)ddv[rt][r] * 2 * 64 + wv * 16 + lc];
            ushort4 hv;
            hv.x = f2bu(silu_f(accn[rt][0][r] + bu2f(us.x)));
            hv.y = f2bu(silu_f(accn[rt][1][r] + bu2f(us.y)));
            hv.z = f2bu(silu_f(accn[rt][2][r] + bu2f(us.z)));
            hv.w = f2bu(silu_f(accn[rt][3][r] + bu2f(us.w)));
            *(ushort4*)&hid[row * HP + wv * 64 + lc * 4] = hv;
        }
    }
    __syncthreads();

    // ---- GEMM2: msg = hid @ Wn2 + bn2 ----
    f32x4 acc2[4][2];
    #pragma unroll
    for (int nti = 0; nti < 2; ++nti) {
        float b = bn2[(wv * 2 + nti) * 16 + lc];
        #pragma unroll
        for (int rt = 0; rt < 4; ++rt) acc2[rt][nti] = (f32x4){b, b, b, b};
    }
    for (int ks = 0; ks < 8; ++ks) {
        bf16x8 a[4];
        #pragma unroll
        for (int rt = 0; rt < 4; ++rt)
            a[rt] = *(const bf16x8*)&hid[(rt * 16 + lc) * HP + ks * 32 + q * 8];
        #pragma unroll
        for (int nti = 0; nti < 2; ++nti) {
            bf16x8 b = *(const bf16x8*)&Wn2s[((ks * 8 + wv * 2 + nti) * 64 + lane) * 8];
            #pragma unroll
            for (int rt = 0; rt < 4; ++rt)
                acc2[rt][nti] = __builtin_amdgcn_mfma_f32_16x16x32_bf16(a[rt], b, acc2[rt][nti], 0, 0, 0);
        }
    }
    __syncthreads();   // waves done reading hid

    // msg col-swizzled (c'' = wv*32 + lc*2 + nti), float2 writes
    float* msg = (float*)smem;
    #pragma unroll
    for (int rt = 0; rt < 4; ++rt)
        #pragma unroll
        for (int r = 0; r < 4; ++r) {
            int row = rt * 16 + q * 4 + r;
            float2 mv; mv.x = acc2[rt][0][r]; mv.y = acc2[rt][1][r];
            *(float2*)&msg[row * MSGP + wv * 32 + lc * 2] = mv;
        }
    __syncthreads();

    // ---- segmented flush: per-(segment, col-group) full-tile sums.
    // Interior segments (exclusive to this block, sorted order) -> plain stores;
    // first/last segments (may span tiles) -> atomics. h_agg lines are node-private.
    {
        int nseg = nseg_sh;
        for (int u = tid; u < nseg * 32; u += 256) {
            int s  = u >> 5;
            int cg = (u & 31) * 4;
            int r0 = seg_start[s], r1 = seg_start[s + 1];
            f32x4 run = (f32x4){0.f, 0.f, 0.f, 0.f};
            for (int r = r0; r < r1; ++r)
                run += *(const f32x4*)&msg[r * MSGP + cg];
            float* dst = &h_agg[(size_t)didx[r0] * ND + cg];
            if (s == 0 || s == nseg - 1) {
                atomicAdd(dst + 0, run[0]); atomicAdd(dst + 1, run[1]);
                atomicAdd(dst + 2, run[2]); atomicAdd(dst + 3, run[3]);
            } else {
                *(f32x4*)dst = run;
            }
        }
        // coord updates: tiny traffic, always atomic (x_agg lines span nodes)
        for (int u = tid; u < nseg * 3; u += 256) {
            int s = u / 3, c = u % 3;
            int r0 = seg_start[s], r1 = seg_start[s + 1];
            float run = 0.f;
            for (int r = r0; r < r1; ++r)
                run += coordw_sh[r] * dir_sh[r * 3 + c];
            atomicAdd(&x_agg[didx[r0] * 3 + c], run);
        }
    }
}

__global__ __launch_bounds__(256) void egnn_finalize(
    const float* __restrict__ h, const float* __restrict__ x,
    const float* __restrict__ h_agg, const float* __restrict__ x_agg,
    float* __restrict__ out, int n_nodes)
{
    int i = blockIdx.x * 256 + threadIdx.x;
    int nh = n_nodes * ND;
    int total = nh + n_nodes * 3;
    if (i < nh) {
        int c = i & 127;
        int csw = (c >> 5) * 32 + (c & 15) * 2 + ((c >> 4) & 1);  // unswizzle msg cols
        out[i] = h[i] + h_agg[(size_t)(i >> 7) * ND + csw];
    } else if (i < total) { int k = i - nh; out[i] = x[k] + x_agg[k]; }
}

extern "C" void kernel_launch(void* const* d_in, const int* in_sizes, int n_in,
                              void* d_out, int out_size, void* d_ws, size_t ws_size,
                              hipStream_t stream)
{
    const float* h    = (const float*)d_in[0];
    const float* x    = (const float*)d_in[1];
    const int*   eidx = (const int*)d_in[2];
    const float* dist = (const float*)d_in[3];
    const float* Wn1  = (const float*)d_in[4];
    const float* bn1  = (const float*)d_in[5];
    const float* Wn2  = (const float*)d_in[6];
    const float* bn2  = (const float*)d_in[7];
    const float* Wc1  = (const float*)d_in[8];
    const float* bc1  = (const float*)d_in[9];
    const float* Wc2  = (const float*)d_in[10];
    const float* We1  = (const float*)d_in[11];
    const float* be1  = (const float*)d_in[12];
    const float* We2  = (const float*)d_in[13];
    const float* be2  = (const float*)d_in[14];

    const int E = in_sizes[3];
    const int N = in_sizes[0] / ND;

    // workspace layout (16B-aligned segments)
    float* h_agg = (float*)d_ws;                           // N*ND (swizzled cols)
    float* x_agg = h_agg + (size_t)N * ND;                 // N*3
    float* bn1p  = x_agg + (size_t)N * 3;                  // HD
    float* bc1p  = bn1p + HD;                              // HD
    __hip_bfloat16* hb   = (__hip_bfloat16*)(bc1p + HD);   // N*ND bf16
    __hip_bfloat16* Wn1s = hb + (size_t)N * ND;            // 81920
    __hip_bfloat16* Wc1s = Wn1s + 81920;                   // 81920
    __hip_bfloat16* Wn2s = Wc1s + 81920;                   // 32768
    int*   cnt   = (int*)(Wn2s + 32768);                   // N
    int*   bsum  = cnt + N;                                // 256
    int*   head  = bsum + 256;                             // N
    int4*  sedge = (int4*)(head + N);                      // E int4
    unsigned short* Q = (unsigned short*)(sedge + E);      // N*512

    hipMemsetAsync(d_ws, 0, ((size_t)N * ND + (size_t)N * 3) * sizeof(float), stream);
    hipMemsetAsync(cnt, 0, (size_t)N * sizeof(int), stream);

    const int nbN = (N + 255) / 256;
    const int nbE = (E + 255) / 256;
    const int nh  = N * ND;
    const int nbH = (nh > E ? nh + 255 : E + 255) / 256;

    prep_h_hist<<<nbH, 256, 0, stream>>>(h, hb, nh, eidx, cnt, E);
    s_scan1  <<<nbN, 256, 0, stream>>>(cnt, bsum, N);
    s_scan2  <<<1,   256, 0, stream>>>(bsum, nbN);
    s_scan3  <<<nbN, 256, 0, stream>>>(cnt, bsum, head, N);
    s_scatter<<<nbE, 256, 0, stream>>>(eidx, dist, head, sedge, E);

    prep_w<<<770, 256, 0, stream>>>(Wn1, Wc1, Wn2, We2, bn1, bc1, be2,
                                    Wn1s, Wc1s, Wn2s, bn1p, bc1p);
    prep_q<<<(N + 63) / 64, 256, 0, stream>>>(hb, Wn1s, Wc1s, Q, N);

    egnn_main<<<(E + ET - 1) / ET, 256, 0, stream>>>(
        hb, x, sedge, Wn1s, Wc1s, Wn2s, Q, bn1p, bc1p, bn2, Wc2,
        We1, be1, h_agg, x_agg, E);

    int total = N * ND + N * 3;
    egnn_finalize<<<(total + 255) / 256, 256, 0, stream>>>(
        h, x, h_agg, x_agg, (float*)d_out, N);
}

// Round 10
// 770.564 us; speedup vs baseline: 1.1128x; 1.0106x over previous
//
#include <hip/hip_runtime.h>
#include <hip/hip_bf16.h>

typedef __attribute__((ext_vector_type(8))) short bf16x8;
typedef __attribute__((ext_vector_type(4))) float f32x4;

constexpr int ND = 128;   // node dim
constexpr int HD = 256;   // hidden dim
constexpr int ED = 64;    // edge dim
constexpr int ET = 64;    // edges per block tile
constexpr int MPn = 200;  // m pitch bf16
constexpr int HP  = 264;  // hid pitch bf16 (528B)
constexpr int MSGP = 132; // msg pitch f32 (528B)

// fast silu: v * rcp(1+exp(-v))
__device__ __forceinline__ float silu_f(float v) {
    float e = __expf(-v);
    return v * __builtin_amdgcn_rcpf(1.0f + e);
}
__device__ __forceinline__ __hip_bfloat16 f2b(float v) { return __float2bfloat16(v); }
__device__ __forceinline__ unsigned short f2bu(float v) {
    __hip_bfloat16 b = __float2bfloat16(v);
    return *(unsigned short*)&b;
}
__device__ __forceinline__ float bu2f(unsigned short u) {
    unsigned int t = ((unsigned int)u) << 16;
    return __uint_as_float(t);
}

// ---------- fused prep A: h->bf16 + dst histogram + weight swizzle + bias fold ----------
__global__ __launch_bounds__(256) void prep_fused_a(
    const float* __restrict__ h, __hip_bfloat16* __restrict__ hb, int nh,
    const int* __restrict__ eidx, int* __restrict__ cnt, int E, int nbH,
    const float* __restrict__ Wn1, const float* __restrict__ Wc1,
    const float* __restrict__ Wn2, const float* __restrict__ We2,
    const float* __restrict__ bn1, const float* __restrict__ bc1,
    const float* __restrict__ be2,
    __hip_bfloat16* __restrict__ Wn1s, __hip_bfloat16* __restrict__ Wc1s,
    __hip_bfloat16* __restrict__ Wn2s,
    float* __restrict__ bn1p, float* __restrict__ bc1p)
{
    if ((int)blockIdx.x < nbH) {
        int i = blockIdx.x * 256 + threadIdx.x;
        if (i < nh) hb[i] = f2b(h[i]);
        if (i < E)  atomicAdd(&cnt[eidx[E + i]], 1);
        return;
    }
    int id = (blockIdx.x - nbH) * 256 + threadIdx.x;
    if (id < 163840) {                      // Wn1s / Wc1s: 10 ks * 16 nt * 64 * 8
        int e = id;
        const float* W = Wn1; __hip_bfloat16* out = Wn1s;
        if (id >= 81920) { e -= 81920; W = Wc1; out = Wc1s; }
        int j = e & 7, lane = (e >> 3) & 63, nt = (e >> 9) & 15, ks = e >> 13;
        int k = ks * 32 + (lane >> 4) * 8 + j;
        int n = nt * 16 + (lane & 15);
        float v;
        if (k < 2 * ND) v = W[k * HD + n];
        else {
            int t = k - 2 * ND; v = 0.f;
            for (int u = 0; u < ED; ++u) v += We2[t * ED + u] * W[(2 * ND + u) * HD + n];
        }
        out[e] = f2b(v);
    } else if (id < 196608) {               // Wn2s: k permuted to swizzled hid cols
        int e = id - 163840;
        int j = e & 7, lane = (e >> 3) & 63, nt = (e >> 9) & 7, ks = e >> 12;
        int kk = ks * 32 + (lane >> 4) * 8 + j;
        int k = (kk >> 6) * 64 + (kk & 3) * 16 + ((kk >> 2) & 15);
        int n = nt * 16 + (lane & 15);
        Wn2s[e] = f2b(Wn2[k * ND + n]);
    } else if (id < 197120) {               // folded biases
        int n = id - 196608;
        if (n < HD) {
            float v = bn1[n];
            for (int t = 0; t < ED; ++t) v += be2[t] * Wn1[(2 * ND + t) * HD + n];
            bn1p[n] = v;
        } else {
            int m = n - HD;
            float v = bc1[m];
            for (int t = 0; t < ED; ++t) v += be2[t] * Wc1[(2 * ND + t) * HD + m];
            bc1p[m] = v;
        }
    }
}

// ---------- counting sort scans ----------
__global__ __launch_bounds__(256) void s_scan1(const int* __restrict__ cnt,
                                               int* __restrict__ bsum, int N) {
    __shared__ int sh[256];
    int i = blockIdx.x * 256 + threadIdx.x;
    sh[threadIdx.x] = (i < N) ? cnt[i] : 0;
    __syncthreads();
    for (int s = 128; s > 0; s >>= 1) {
        if (threadIdx.x < s) sh[threadIdx.x] += sh[threadIdx.x + s];
        __syncthreads();
    }
    if (threadIdx.x == 0) bsum[blockIdx.x] = sh[0];
}

__global__ __launch_bounds__(256) void s_scan2(int* __restrict__ bsum, int nb) {
    __shared__ int sh[256];
    int t = threadIdx.x;
    int orig = (t < nb) ? bsum[t] : 0;
    sh[t] = orig;
    __syncthreads();
    for (int off = 1; off < 256; off <<= 1) {
        int u = (t >= off) ? sh[t - off] : 0;
        __syncthreads();
        sh[t] += u;
        __syncthreads();
    }
    if (t < nb) bsum[t] = sh[t] - orig;   // exclusive
}

__global__ __launch_bounds__(256) void s_scan3(const int* __restrict__ cnt,
                                               const int* __restrict__ bsum,
                                               int* __restrict__ head, int N) {
    __shared__ int sh[256];
    int t = threadIdx.x, i = blockIdx.x * 256 + t;
    int v = (i < N) ? cnt[i] : 0;
    sh[t] = v;
    __syncthreads();
    for (int off = 1; off < 256; off <<= 1) {
        int u = (t >= off) ? sh[t - off] : 0;
        __syncthreads();
        sh[t] += u;
        __syncthreads();
    }
    if (i < N) head[i] = bsum[blockIdx.x] + sh[t] - v;  // exclusive prefix
}

// ---------- fused prep B: edge scatter + Q GEMM ----------
__global__ __launch_bounds__(256) void prep_fused_b(
    const int* __restrict__ eidx, const float* __restrict__ dist,
    int* __restrict__ head, int4* __restrict__ sedge, int E, int nbE,
    const __hip_bfloat16* __restrict__ hb,
    const __hip_bfloat16* __restrict__ Wn1s,
    const __hip_bfloat16* __restrict__ Wc1s,
    unsigned short* __restrict__ Q, int N)
{
    __shared__ __align__(16) __hip_bfloat16 a_sh[64 * 136];
    if ((int)blockIdx.x < nbE) {
        int e = blockIdx.x * 256 + threadIdx.x;
        if (e < E) {
            int d = eidx[E + e];
            int pos = atomicAdd(&head[d], 1);
            int4 v; v.x = eidx[e]; v.y = d; v.z = __float_as_int(dist[e]); v.w = 0;
            sedge[pos] = v;
        }
        return;
    }
    // ---- prep_q part ----
    const int tid = threadIdx.x;
    const int lane = tid & 63, wv = tid >> 6;
    const int q = lane >> 4, lc = lane & 15;
    const int row0 = (blockIdx.x - nbE) * 64;

    for (int i = tid; i < 64 * 16; i += 256) {
        int r = i >> 4, piece = i & 15;
        int node = min(row0 + r, N - 1);
        uint4 v = ((const uint4*)(hb + (size_t)node * ND))[piece];
        *((uint4*)((char*)a_sh + r * 272 + piece * 16)) = v;
    }
    __syncthreads();

    for (int pass = 0; pass < 2; ++pass) {
        const __hip_bfloat16* Ws = pass ? Wc1s : Wn1s;
        f32x4 acc[4][4];
        #pragma unroll
        for (int rt = 0; rt < 4; ++rt)
            #pragma unroll
            for (int nti = 0; nti < 4; ++nti) acc[rt][nti] = (f32x4){0.f, 0.f, 0.f, 0.f};

        for (int ks = 0; ks < 4; ++ks) {
            bf16x8 a[4];
            #pragma unroll
            for (int rt = 0; rt < 4; ++rt)
                a[rt] = *(const bf16x8*)&a_sh[(rt * 16 + lc) * 136 + ks * 32 + q * 8];
            #pragma unroll
            for (int nti = 0; nti < 4; ++nti) {
                bf16x8 b = *(const bf16x8*)&Ws[(((ks + 4) * 16 + wv * 4 + nti) * 64 + lane) * 8];
                #pragma unroll
                for (int rt = 0; rt < 4; ++rt)
                    acc[rt][nti] = __builtin_amdgcn_mfma_f32_16x16x32_bf16(a[rt], b, acc[rt][nti], 0, 0, 0);
            }
        }
        #pragma unroll
        for (int rt = 0; rt < 4; ++rt)
            #pragma unroll
            for (int r = 0; r < 4; ++r) {
                int node = row0 + rt * 16 + q * 4 + r;
                if (node < N) {
                    ushort4 us;
                    us.x = f2bu(acc[rt][0][r]); us.y = f2bu(acc[rt][1][r]);
                    us.z = f2bu(acc[rt][2][r]); us.w = f2bu(acc[rt][3][r]);
                    ((ushort4*)Q)[((size_t)node * 2 + pass) * 64 + wv * 16 + lc] = us;
                }
            }
    }
}

// ---------- main fused edge kernel ----------
__global__ __launch_bounds__(256, 4) void egnn_main(
    const __hip_bfloat16* __restrict__ hb,
    const float* __restrict__ x,
    const int4* __restrict__ sedge,
    const __hip_bfloat16* __restrict__ Wn1s,
    const __hip_bfloat16* __restrict__ Wc1s,
    const __hip_bfloat16* __restrict__ Wn2s,
    const unsigned short* __restrict__ Q,
    const float* __restrict__ bn1p, const float* __restrict__ bc1p,
    const float* __restrict__ bn2,  const float* __restrict__ Wc2,
    const float* __restrict__ We1,  const float* __restrict__ be1,
    float* __restrict__ h_agg, float* __restrict__ x_agg,
    int E)
{
    __shared__ __align__(16) unsigned char smem[ET * HP * 2];
    __shared__ float dir_sh[ET * 3];
    __shared__ float coordw_part[4][ET];   // per-wave partials, no atomics
    __shared__ float dist_sh[ET];
    __shared__ int   sidx[ET], didx[ET];
    __shared__ int   seg_start[ET + 1];
    __shared__ int   nseg_sh;

    __hip_bfloat16* m_sh = (__hip_bfloat16*)smem;

    const int tid  = threadIdx.x;
    const int lane = tid & 63;
    const int wv   = tid >> 6;
    const int q    = lane >> 4;
    const int lc   = lane & 15;
    const int e0   = blockIdx.x * ET;
    const int nv   = min(ET, E - e0);

    if (tid < ET) {
        int e = min(e0 + tid, E - 1);
        int4 v = sedge[e];
        int s = v.x, d = v.y;
        sidx[tid] = s; didx[tid] = d;
        dist_sh[tid] = __int_as_float(v.z);
        #pragma unroll
        for (int c = 0; c < 3; ++c) dir_sh[tid * 3 + c] = x[s * 3 + c] - x[d * 3 + c];
    }
    __syncthreads();

    // segment table (wave 0 only)
    if (wv == 0) {
        bool valid = lane < nv;
        bool flag = valid && (lane == 0 || didx[lane] != didx[lane - 1]);
        unsigned long long mask = __ballot(flag);
        if (flag) {
            int s = __popcll(mask & ((1ull << lane) - 1ull));
            seg_start[s] = lane;
        }
        if (lane == 0) {
            int ns = __popcll(mask);
            nseg_sh = ns;
            seg_start[ns] = nv;
        }
    }

    // gather h[src] -> m[:,0:128]
    for (int i = tid; i < ET * 16; i += 256) {
        int er = i >> 4, piece = i & 15;
        uint4 v = ((const uint4*)(hb + (size_t)sidx[er] * ND))[piece];
        *((uint4*)((char*)m_sh + er * (MPn * 2) + piece * 16)) = v;
    }
    // se = silu(dist*We1+be1) -> m[:,128:192]
    for (int i = tid; i < ET * ED; i += 256) {
        int er = i >> 6, j = i & 63;
        m_sh[er * MPn + ND + j] = f2b(silu_f(fmaf(dist_sh[er], We1[j], be1[j])));
    }
    __syncthreads();

    int ddv[4][4];
    #pragma unroll
    for (int rt = 0; rt < 4; ++rt)
        #pragma unroll
        for (int r = 0; r < 4; ++r) ddv[rt][r] = didx[rt * 16 + q * 4 + r];

    // prefetch coord-pass Q (consumed in epilogue A; hidden under GEMM1-A)
    ushort4 qA[4][4];
    #pragma unroll
    for (int rt = 0; rt < 4; ++rt)
        #pragma unroll
        for (int r = 0; r < 4; ++r)
            qA[rt][r] = ((const ushort4*)Q)[((size_t)ddv[rt][r] * 2 + 1) * 64 + wv * 16 + lc];

    // ---- GEMM1 pass A: coord hidden ----
    {
        f32x4 acc[4][4];
        #pragma unroll
        for (int nti = 0; nti < 4; ++nti) {
            float b = bc1p[(wv * 4 + nti) * 16 + lc];
            #pragma unroll
            for (int rt = 0; rt < 4; ++rt) acc[rt][nti] = (f32x4){b, b, b, b};
        }
        for (int ks = 0; ks < 6; ++ks) {
            int bk = (ks < 4) ? ks : ks + 4;
            bf16x8 a[4];
            #pragma unroll
            for (int rt = 0; rt < 4; ++rt)
                a[rt] = *(const bf16x8*)&m_sh[(rt * 16 + lc) * MPn + ks * 32 + q * 8];
            #pragma unroll
            for (int nti = 0; nti < 4; ++nti) {
                bf16x8 b = *(const bf16x8*)&Wc1s[((bk * 16 + wv * 4 + nti) * 64 + lane) * 8];
                #pragma unroll
                for (int rt = 0; rt < 4; ++rt)
                    acc[rt][nti] = __builtin_amdgcn_mfma_f32_16x16x32_bf16(a[rt], b, acc[rt][nti], 0, 0, 0);
            }
        }
        float wcv[4];
        #pragma unroll
        for (int nti = 0; nti < 4; ++nti) wcv[nti] = Wc2[(wv * 4 + nti) * 16 + lc];
        #pragma unroll
        for (int rt = 0; rt < 4; ++rt) {
            #pragma unroll
            for (int r = 0; r < 4; ++r) {
                ushort4 us = qA[rt][r];
                float pv = 0.f;
                pv += silu_f(acc[rt][0][r] + bu2f(us.x)) * wcv[0];
                pv += silu_f(acc[rt][1][r] + bu2f(us.y)) * wcv[1];
                pv += silu_f(acc[rt][2][r] + bu2f(us.z)) * wcv[2];
                pv += silu_f(acc[rt][3][r] + bu2f(us.w)) * wcv[3];
                pv += __shfl_xor(pv, 1); pv += __shfl_xor(pv, 2);
                pv += __shfl_xor(pv, 4); pv += __shfl_xor(pv, 8);
                if (lc == 0) coordw_part[wv][rt * 16 + q * 4 + r] = pv;
            }
        }
    }

    // prefetch node-pass Q (consumed in hid write; hidden under GEMM1-B)
    ushort4 qB[4][4];
    #pragma unroll
    for (int rt = 0; rt < 4; ++rt)
        #pragma unroll
        for (int r = 0; r < 4; ++r)
            qB[rt][r] = ((const ushort4*)Q)[(size_t)ddv[rt][r] * 2 * 64 + wv * 16 + lc];

    // ---- GEMM1 pass B: node hidden ----
    f32x4 accn[4][4];
    #pragma unroll
    for (int nti = 0; nti < 4; ++nti) {
        float b = bn1p[(wv * 4 + nti) * 16 + lc];
        #pragma unroll
        for (int rt = 0; rt < 4; ++rt) accn[rt][nti] = (f32x4){b, b, b, b};
    }
    for (int ks = 0; ks < 6; ++ks) {
        int bk = (ks < 4) ? ks : ks + 4;
        bf16x8 a[4];
        #pragma unroll
        for (int rt = 0; rt < 4; ++rt)
            a[rt] = *(const bf16x8*)&m_sh[(rt * 16 + lc) * MPn + ks * 32 + q * 8];
        #pragma unroll
        for (int nti = 0; nti < 4; ++nti) {
            bf16x8 b = *(const bf16x8*)&Wn1s[((bk * 16 + wv * 4 + nti) * 64 + lane) * 8];
            #pragma unroll
            for (int rt = 0; rt < 4; ++rt)
                accn[rt][nti] = __builtin_amdgcn_mfma_f32_16x16x32_bf16(a[rt], b, accn[rt][nti], 0, 0, 0);
        }
    }
    __syncthreads();   // all waves done reading m_sh

    // hid = silu(accn + qB), col-swizzled (c' = wv*64 + lc*4 + nti)
    __hip_bfloat16* hid = (__hip_bfloat16*)smem;
    #pragma unroll
    for (int rt = 0; rt < 4; ++rt) {
        #pragma unroll
        for (int r = 0; r < 4; ++r) {
            int row = rt * 16 + q * 4 + r;
            ushort4 us = qB[rt][r];
            ushort4 hv;
            hv.x = f2bu(silu_f(accn[rt][0][r] + bu2f(us.x)));
            hv.y = f2bu(silu_f(accn[rt][1][r] + bu2f(us.y)));
            hv.z = f2bu(silu_f(accn[rt][2][r] + bu2f(us.z)));
            hv.w = f2bu(silu_f(accn[rt][3][r] + bu2f(us.w)));
            *(ushort4*)&hid[row * HP + wv * 64 + lc * 4] = hv;
        }
    }
    __syncthreads();

    // ---- GEMM2: msg = hid @ Wn2 + bn2 ----
    f32x4 acc2[4][2];
    #pragma unroll
    for (int nti = 0; nti < 2; ++nti) {
        float b = bn2[(wv * 2 + nti) * 16 + lc];
        #pragma unroll
        for (int rt = 0; rt < 4; ++rt) acc2[rt][nti] = (f32x4){b, b, b, b};
    }
    for (int ks = 0; ks < 8; ++ks) {
        bf16x8 a[4];
        #pragma unroll
        for (int rt = 0; rt < 4; ++rt)
            a[rt] = *(const bf16x8*)&hid[(rt * 16 + lc) * HP + ks * 32 + q * 8];
        #pragma unroll
        for (int nti = 0; nti < 2; ++nti) {
            bf16x8 b = *(const bf16x8*)&Wn2s[((ks * 8 + wv * 2 + nti) * 64 + lane) * 8];
            #pragma unroll
            for (int rt = 0; rt < 4; ++rt)
                acc2[rt][nti] = __builtin_amdgcn_mfma_f32_16x16x32_bf16(a[rt], b, acc2[rt][nti], 0, 0, 0);
        }
    }
    __syncthreads();   // waves done reading hid

    // msg col-swizzled (c'' = wv*32 + lc*2 + nti), float2 writes
    float* msg = (float*)smem;
    #pragma unroll
    for (int rt = 0; rt < 4; ++rt)
        #pragma unroll
        for (int r = 0; r < 4; ++r) {
            int row = rt * 16 + q * 4 + r;
            float2 mv; mv.x = acc2[rt][0][r]; mv.y = acc2[rt][1][r];
            *(float2*)&msg[row * MSGP + wv * 32 + lc * 2] = mv;
        }
    __syncthreads();

    // ---- segmented flush: interior segments plain stores, boundary atomics ----
    {
        int nseg = nseg_sh;
        for (int u = tid; u < nseg * 32; u += 256) {
            int s  = u >> 5;
            int cg = (u & 31) * 4;
            int r0 = seg_start[s], r1 = seg_start[s + 1];
            f32x4 run = (f32x4){0.f, 0.f, 0.f, 0.f};
            for (int r = r0; r < r1; ++r)
                run += *(const f32x4*)&msg[r * MSGP + cg];
            float* dst = &h_agg[(size_t)didx[r0] * ND + cg];
            if (s == 0 || s == nseg - 1) {
                atomicAdd(dst + 0, run[0]); atomicAdd(dst + 1, run[1]);
                atomicAdd(dst + 2, run[2]); atomicAdd(dst + 3, run[3]);
            } else {
                *(f32x4*)dst = run;
            }
        }
        for (int u = tid; u < nseg * 3; u += 256) {
            int s = u / 3, c = u % 3;
            int r0 = seg_start[s], r1 = seg_start[s + 1];
            float run = 0.f;
            for (int r = r0; r < r1; ++r) {
                float w = coordw_part[0][r] + coordw_part[1][r]
                        + coordw_part[2][r] + coordw_part[3][r];
                run += w * dir_sh[r * 3 + c];
            }
            atomicAdd(&x_agg[didx[r0] * 3 + c], run);
        }
    }
}

__global__ __launch_bounds__(256) void egnn_finalize(
    const float* __restrict__ h, const float* __restrict__ x,
    const float* __restrict__ h_agg, const float* __restrict__ x_agg,
    float* __restrict__ out, int n_nodes)
{
    int i = blockIdx.x * 256 + threadIdx.x;
    int nh = n_nodes * ND;
    int total = nh + n_nodes * 3;
    if (i < nh) {
        int c = i & 127;
        int csw = (c >> 5) * 32 + (c & 15) * 2 + ((c >> 4) & 1);  // unswizzle msg cols
        out[i] = h[i] + h_agg[(size_t)(i >> 7) * ND + csw];
    } else if (i < total) { int k = i - nh; out[i] = x[k] + x_agg[k]; }
}

extern "C" void kernel_launch(void* const* d_in, const int* in_sizes, int n_in,
                              void* d_out, int out_size, void* d_ws, size_t ws_size,
                              hipStream_t stream)
{
    const float* h    = (const float*)d_in[0];
    const float* x    = (const float*)d_in[1];
    const int*   eidx = (const int*)d_in[2];
    const float* dist = (const float*)d_in[3];
    const float* Wn1  = (const float*)d_in[4];
    const float* bn1  = (const float*)d_in[5];
    const float* Wn2  = (const float*)d_in[6];
    const float* bn2  = (const float*)d_in[7];
    const float* Wc1  = (const float*)d_in[8];
    const float* bc1  = (const float*)d_in[9];
    const float* Wc2  = (const float*)d_in[10];
    const float* We1  = (const float*)d_in[11];
    const float* be1  = (const float*)d_in[12];
    const float* We2  = (const float*)d_in[13];
    const float* be2  = (const float*)d_in[14];

    const int E = in_sizes[3];
    const int N = in_sizes[0] / ND;

    // workspace layout (16B-aligned segments)
    float* h_agg = (float*)d_ws;                           // N*ND (swizzled cols)
    float* x_agg = h_agg + (size_t)N * ND;                 // N*3
    float* bn1p  = x_agg + (size_t)N * 3;                  // HD
    float* bc1p  = bn1p + HD;                              // HD
    __hip_bfloat16* hb   = (__hip_bfloat16*)(bc1p + HD);   // N*ND bf16
    __hip_bfloat16* Wn1s = hb + (size_t)N * ND;            // 81920
    __hip_bfloat16* Wc1s = Wn1s + 81920;                   // 81920
    __hip_bfloat16* Wn2s = Wc1s + 81920;                   // 32768
    int*   cnt   = (int*)(Wn2s + 32768);                   // N
    int*   bsum  = cnt + N;                                // 256
    int*   head  = bsum + 256;                             // N
    int4*  sedge = (int4*)(head + N);                      // E int4
    unsigned short* Q = (unsigned short*)(sedge + E);      // N*512

    hipMemsetAsync(d_ws, 0, ((size_t)N * ND + (size_t)N * 3) * sizeof(float), stream);
    hipMemsetAsync(cnt, 0, (size_t)N * sizeof(int), stream);

    const int nbN = (N + 255) / 256;
    const int nbE = (E + 255) / 256;
    const int nh  = N * ND;
    const int nbH = (nh > E ? nh + 255 : E + 255) / 256;
    const int nbQ = (N + 63) / 64;

    prep_fused_a<<<nbH + 770, 256, 0, stream>>>(
        h, hb, nh, eidx, cnt, E, nbH,
        Wn1, Wc1, Wn2, We2, bn1, bc1, be2, Wn1s, Wc1s, Wn2s, bn1p, bc1p);
    s_scan1<<<nbN, 256, 0, stream>>>(cnt, bsum, N);
    s_scan2<<<1,   256, 0, stream>>>(bsum, nbN);
    s_scan3<<<nbN, 256, 0, stream>>>(cnt, bsum, head, N);
    prep_fused_b<<<nbE + nbQ, 256, 0, stream>>>(
        eidx, dist, head, sedge, E, nbE, hb, Wn1s, Wc1s, Q, N);

    egnn_main<<<(E + ET - 1) / ET, 256, 0, stream>>>(
        hb, x, sedge, Wn1s, Wc1s, Wn2s, Q, bn1p, bc1p, bn2, Wc2,
        We1, be1, h_agg, x_agg, E);

    int total = N * ND + N * 3;
    egnn_finalize<<<(total + 255) / 256, 256, 0, stream>>>(
        h, x, h_agg, x_agg, (float*)d_out, N);
}